// Round 5
// baseline (285.389 us; speedup 1.0000x reference)
//
#include <hip/hip_runtime.h>
#include <stdint.h>

#define B_SZ   2048
#define IN_SZ  1024
#define OUT_SZ 1024
#define Q_SZ   16
#define K_EXP  (Q_SZ * IN_SZ)   // 16384

typedef __attribute__((ext_vector_type(8))) short short8;   // 8 bf16 (4 VGPRs)
typedef __attribute__((ext_vector_type(4))) float floatx4;  // MFMA accumulator
typedef __attribute__((ext_vector_type(2))) unsigned short u16x2;

__device__ __forceinline__ unsigned short f32_to_bf16_rne(float f) {
    union { float f; uint32_t u; } v; v.f = f;
    uint32_t u = v.u;
    return (unsigned short)((u + 0x7FFFu + ((u >> 16) & 1u)) >> 16);
}

__device__ __forceinline__ void gll16(const void* g, void* l) {
    // async global->LDS, 16B/lane; LDS dst is wave-uniform base + lane*16
    __builtin_amdgcn_global_load_lds(
        (const __attribute__((address_space(1))) void*)g,
        (__attribute__((address_space(3))) void*)l, 16, 0, 0);
}

// packed 2x16-bit: out = (iv16==q16) ? xv16 : 0.  4 VALU ops via v_pk_min_u16:
// t = iv^qq; m = min(t,1)-1 (0xFFFF iff t==0, else 0); return x & m.  Exact.
__device__ __forceinline__ uint32_t mask2(uint32_t xv, uint32_t iv, uint32_t qq) {
    union { uint32_t u; u16x2 v; } t, m;
    t.u = iv ^ qq;
    u16x2 one; one.x = 1; one.y = 1;
    m.v = __builtin_elementwise_min(t.v, one) - one;
    return xv & m.u;
}

// ---------------- prep 1: out[b][o] = bias[o] ----------------
__global__ void k_init_out(float* __restrict__ out, const float* __restrict__ bias) {
    int t = blockIdx.x * 256 + threadIdx.x;        // float4 index, 524288 total
    const float4* b4 = (const float4*)bias;
    ((float4*)out)[t] = b4[t & 255];               // 256 float4 per row of 1024
}

// ---------------- prep 2: x -> bf16, idx -> u16 ----------------
__global__ void k_prep_xi(const float* __restrict__ x, const int* __restrict__ idx,
                          unsigned short* __restrict__ xb16, unsigned short* __restrict__ idxh) {
    int t = blockIdx.x * 256 + threadIdx.x;        // 262144 threads, 8 elems each
    int b  = t >> 7;
    int c  = (t & 127) << 3;
    const float* xp = x + (size_t)b * IN_SZ + c;
    const int*   ip = idx + (size_t)b * IN_SZ + c;
    float xv[8]; int iv[8];
    *(float4*)(xv)     = ((const float4*)xp)[0];
    *(float4*)(xv + 4) = ((const float4*)xp)[1];
    *(int4*)(iv)       = ((const int4*)ip)[0];
    *(int4*)(iv + 4)   = ((const int4*)ip)[1];
    unsigned short xo[8], io8[8];
#pragma unroll
    for (int j = 0; j < 8; ++j) { xo[j] = f32_to_bf16_rne(xv[j]); io8[j] = (unsigned short)iv[j]; }
    *(uint4*)(xb16 + (size_t)b * IN_SZ + c) = *(uint4*)xo;
    *(uint4*)(idxh + (size_t)b * IN_SZ + c) = *(uint4*)io8;
}

// ---------------- prep 3: Wt[o][q*IN+i] = bf16(W[q*IN+i][o])  (transpose+convert) ----
__global__ void k_build_wt(const float* __restrict__ W, unsigned short* __restrict__ Wt) {
    __shared__ float tile[64][65];                 // +1 pad breaks bank conflicts
    int t = threadIdx.x;
    int k0 = blockIdx.x * 64;                      // 256 k-tiles
    int o0 = blockIdx.y * 64;                      // 16 o-tiles
#pragma unroll
    for (int it = 0; it < 4; ++it) {
        int F = it * 256 + t;                      // 1024 float4 loads
        int row = F >> 4;
        int c4  = (F & 15) * 4;
        float4 v = *(const float4*)(W + (size_t)(k0 + row) * OUT_SZ + o0 + c4);
        tile[row][c4 + 0] = v.x; tile[row][c4 + 1] = v.y;
        tile[row][c4 + 2] = v.z; tile[row][c4 + 3] = v.w;
    }
    __syncthreads();
#pragma unroll
    for (int it = 0; it < 2; ++it) {
        int G = it * 256 + t;                      // 512 uint4 stores
        int oo = G >> 3;
        int kc = (G & 7) * 8;
        unsigned short ov[8];
#pragma unroll
        for (int j = 0; j < 8; ++j) ov[j] = f32_to_bf16_rne(tile[kc + j][oo]);
        *(uint4*)(Wt + (size_t)(o0 + oo) * K_EXP + k0 + kc) = *(uint4*)ov;
    }
}

// ---------------- fused GEMM: out += maskq(x) @ Wt^T over the block's i-window ----
// z-block owns i in [zb*128, zb*128+128), ALL q. 32 steps = 2 i-halves x 16 q.
// Only Wt is LDS-staged (16 KB/step, ping-pong, ONE barrier per step); x/idx live
// in registers. Wave tile: 32 b-rows x 128 o-cols (2 mt x 8 nt of 16x16x32 MFMA).
__global__ __launch_bounds__(256, 4) void k_gemm(const unsigned short* __restrict__ Wt,
                                                 const unsigned short* __restrict__ xb16,
                                                 const unsigned short* __restrict__ idxh,
                                                 float* __restrict__ out) {
    __shared__ unsigned short Blds[2 * 128 * 64];  // 32 KB ping-pong
    const int tid  = threadIdx.x;
    const int wave = tid >> 6, lane = tid & 63;

    // 1-D grid, id = zb + 8*xb + 64*yb -> XCD (id%8) = zb: all blocks on one XCD
    // share the same Wt column window (4 MB = exactly one XCD L2).
    const int id = blockIdx.x;
    const int zb = id & 7;
    const int o0 = ((id >> 3) & 7) * 128;
    const int b0 = (id >> 6) * 128;
    const int ibase = zb * 128;                    // i-window

    // Wt staging: wave w rows [w*32+g*8+lrow], 128B rows = 8 chunks, slot = c^(row&7)
    const int lrow = lane >> 3, lcol = lane & 7;
    const int scol = lcol ^ lrow;
    const unsigned short* wS = Wt + (size_t)(o0 + wave * 32 + lrow) * K_EXP + ibase + scol * 8;
    char* wDb = (char*)Blds + wave * 4096;

    // B-frag offsets: row = nt*16 + (lane&15); chunk c = h*4 + quad at slot c^(lane&7)
    int nb[8];
#pragma unroll
    for (int nt = 0; nt < 8; ++nt) nb[nt] = (nt * 16 + (lane & 15)) * 128;
    int so[2];
#pragma unroll
    for (int h = 0; h < 2; ++h) so[h] = (((h << 2) | (lane >> 4)) ^ lcol) * 16;

    // A-side: row b0 + wave*32 + mt*16 + (lane&15); k-bytes per (h,quad) cover a full line
    const int arow = b0 + wave * 32 + (lane & 15);
    const unsigned short* xg = xb16 + (size_t)arow * IN_SZ + ibase + (lane >> 4) * 8;
    const unsigned short* ig = idxh + (size_t)arow * IN_SZ + ibase + (lane >> 4) * 8;

    floatx4 acc[16];
#pragma unroll
    for (int i = 0; i < 16; ++i) acc[i] = (floatx4){0.f, 0.f, 0.f, 0.f};

    // stage step s into buf (s&1): Wt cols (s&15)*1024 + (s>>4)*64 within window
#define STAGE(s)                                                              \
    {   int cw_ = ((s) & 15) * 1024 + (((s) >> 4) & 1) * 64;                  \
        char* d_ = wDb + (((s) & 1) << 14);                                   \
        _Pragma("unroll")                                                     \
        for (int g_ = 0; g_ < 4; ++g_)                                        \
            gll16(wS + cw_ + (size_t)g_ * 8 * K_EXP, d_ + g_ * 1024);         \
    }

    STAGE(0);
    uint4 xr[2][2], ir[2][2];

    for (int s = 0; s < 32; ++s) {
        __syncthreads();                           // buf[s&1] staged & prior readers done
        if (s < 31) STAGE(s + 1);                  // lands during compute(s)
        if ((s & 15) == 0) {                       // new i-half: reload A regs (uniform)
            int io = (s >> 4) * 64;
#pragma unroll
            for (int mt = 0; mt < 2; ++mt)
#pragma unroll
                for (int h = 0; h < 2; ++h) {
                    xr[mt][h] = *(const uint4*)(xg + mt * 16 * IN_SZ + io + h * 32);
                    ir[mt][h] = *(const uint4*)(ig + mt * 16 * IN_SZ + io + h * 32);
                }
        }
        const uint32_t qq = (uint32_t)(s & 15) * 0x00010001u;
        const char* bB = (const char*)Blds + ((s & 1) << 14);
#pragma unroll
        for (int h = 0; h < 2; ++h) {
            union { uint4 u; short8 s8; } aF[2];
#pragma unroll
            for (int mt = 0; mt < 2; ++mt) {
                aF[mt].u.x = mask2(xr[mt][h].x, ir[mt][h].x, qq);
                aF[mt].u.y = mask2(xr[mt][h].y, ir[mt][h].y, qq);
                aF[mt].u.z = mask2(xr[mt][h].z, ir[mt][h].z, qq);
                aF[mt].u.w = mask2(xr[mt][h].w, ir[mt][h].w, qq);
            }
            short8 bF[8];
#pragma unroll
            for (int nt = 0; nt < 8; ++nt) bF[nt] = *(const short8*)(bB + nb[nt] + so[h]);
#pragma unroll
            for (int mt = 0; mt < 2; ++mt)
#pragma unroll
                for (int nt = 0; nt < 8; ++nt)
                    acc[mt * 8 + nt] = __builtin_amdgcn_mfma_f32_16x16x32_bf16(
                        aF[mt].s8, bF[nt], acc[mt * 8 + nt], 0, 0, 0);
        }
        // single barrier per step: next iteration's barrier protects buf reuse
    }

    // epilogue: C/D col=lane&15 (o), row=(lane>>4)*4+reg (b)
    int cn = lane & 15, rq = lane >> 4;
#pragma unroll
    for (int mt = 0; mt < 2; ++mt)
#pragma unroll
        for (int nt = 0; nt < 8; ++nt) {
            int bb = b0 + wave * 32 + mt * 16 + rq * 4;
            int oo = o0 + nt * 16 + cn;
#pragma unroll
            for (int e = 0; e < 4; ++e)
                atomicAdd(out + (size_t)(bb + e) * OUT_SZ + oo, acc[mt * 8 + nt][e]);
        }
#undef STAGE
}

// ---------------- fallback (ws too small): exact fp32 gather ----------------
__global__ void k_naive(const float* __restrict__ x, const int* __restrict__ idx,
                        const float* __restrict__ W, const float* __restrict__ bias,
                        float* __restrict__ out) {
    int b = blockIdx.x;
    int o = threadIdx.x * 4;
    float4 acc = *(const float4*)(bias + o);
    const float* xr = x + (size_t)b * IN_SZ;
    const int*   ir = idx + (size_t)b * IN_SZ;
    for (int i = 0; i < IN_SZ; ++i) {
        float xv = xr[i];
        int q = ir[i];
        float4 w4 = *(const float4*)(W + ((size_t)q * IN_SZ + i) * OUT_SZ + o);
        acc.x += xv * w4.x; acc.y += xv * w4.y;
        acc.z += xv * w4.z; acc.w += xv * w4.w;
    }
    *(float4*)(out + (size_t)b * OUT_SZ + o) = acc;
}

extern "C" void kernel_launch(void* const* d_in, const int* in_sizes, int n_in,
                              void* d_out, int out_size, void* d_ws, size_t ws_size,
                              hipStream_t stream) {
    const float* x    = (const float*)d_in[0];
    const int*   idx  = (const int*)d_in[1];
    const float* W    = (const float*)d_in[2];
    const float* bias = (const float*)d_in[3];
    float* out = (float*)d_out;

    const size_t wt_elems = (size_t)OUT_SZ * K_EXP;          // 16M u16 = 32 MB
    const size_t x_elems  = (size_t)B_SZ * IN_SZ;            // 2M u16 = 4 MB
    if (ws_size < (wt_elems + 2 * x_elems) * sizeof(unsigned short)) {
        k_naive<<<dim3(B_SZ), dim3(256), 0, stream>>>(x, idx, W, bias, out);
        return;
    }
    unsigned short* Wt   = (unsigned short*)d_ws;
    unsigned short* xb16 = Wt + wt_elems;
    unsigned short* idxh = xb16 + x_elems;

    k_init_out<<<dim3(2048), dim3(256), 0, stream>>>(out, bias);
    k_prep_xi<<<dim3(1024), dim3(256), 0, stream>>>(x, idx, xb16, idxh);
    k_build_wt<<<dim3(256, 16), dim3(256), 0, stream>>>(W, Wt);
    k_gemm<<<dim3(8 * 8 * (B_SZ / 128)), dim3(256), 0, stream>>>(Wt, xb16, idxh, out);
}

// Round 6
// 229.878 us; speedup vs baseline: 1.2415x; 1.2415x over previous
//
#include <hip/hip_runtime.h>
#include <stdint.h>

#define B_SZ   2048
#define IN_SZ  1024
#define OUT_SZ 1024
#define Q_SZ   16
#define K_EXP  (Q_SZ * IN_SZ)   // 16384

typedef __attribute__((ext_vector_type(8))) short short8;   // 8 bf16 (4 VGPRs)
typedef __attribute__((ext_vector_type(4))) float floatx4;  // MFMA accumulator
typedef __attribute__((ext_vector_type(2))) unsigned short u16x2;

__device__ __forceinline__ unsigned short f32_to_bf16_rne(float f) {
    union { float f; uint32_t u; } v; v.f = f;
    uint32_t u = v.u;
    return (unsigned short)((u + 0x7FFFu + ((u >> 16) & 1u)) >> 16);
}

__device__ __forceinline__ void gll16(const void* g, void* l) {
    // async global->LDS, 16B/lane; LDS dst is wave-uniform base + lane*16
    __builtin_amdgcn_global_load_lds(
        (const __attribute__((address_space(1))) void*)g,
        (__attribute__((address_space(3))) void*)l, 16, 0, 0);
}

// Raw barrier with fine-grained vmcnt: NEVER drain to 0 in steady state, so
// async staging stays in flight across the barrier (the m97-ceiling fix).
__device__ __forceinline__ void bar_vm4() {
    asm volatile("s_waitcnt vmcnt(4)\n\ts_barrier" ::: "memory");
}
__device__ __forceinline__ void bar_vm0() {
    asm volatile("s_waitcnt vmcnt(0)\n\ts_barrier" ::: "memory");
}

// packed 2x16-bit: out = (iv16==q16) ? xv16 : 0.  4 VALU ops via v_pk_min_u16:
// t = iv^qq; m = min(t,1)-1 (0xFFFF iff t==0, else 0); return x & m.  Exact.
__device__ __forceinline__ uint32_t mask2(uint32_t xv, uint32_t iv, uint32_t qq) {
    union { uint32_t u; u16x2 v; } t, m;
    t.u = iv ^ qq;
    u16x2 one; one.x = 1; one.y = 1;
    m.v = __builtin_elementwise_min(t.v, one) - one;
    return xv & m.u;
}

// ---------------- prep 1: out[b][o] = bias[o] ----------------
__global__ void k_init_out(float* __restrict__ out, const float* __restrict__ bias) {
    int t = blockIdx.x * 256 + threadIdx.x;        // float4 index, 524288 total
    const float4* b4 = (const float4*)bias;
    ((float4*)out)[t] = b4[t & 255];               // 256 float4 per row of 1024
}

// ---------------- prep 2: x -> bf16, idx -> u16 ----------------
__global__ void k_prep_xi(const float* __restrict__ x, const int* __restrict__ idx,
                          unsigned short* __restrict__ xb16, unsigned short* __restrict__ idxh) {
    int t = blockIdx.x * 256 + threadIdx.x;        // 262144 threads, 8 elems each
    int b  = t >> 7;
    int c  = (t & 127) << 3;
    const float* xp = x + (size_t)b * IN_SZ + c;
    const int*   ip = idx + (size_t)b * IN_SZ + c;
    float xv[8]; int iv[8];
    *(float4*)(xv)     = ((const float4*)xp)[0];
    *(float4*)(xv + 4) = ((const float4*)xp)[1];
    *(int4*)(iv)       = ((const int4*)ip)[0];
    *(int4*)(iv + 4)   = ((const int4*)ip)[1];
    unsigned short xo[8], io8[8];
#pragma unroll
    for (int j = 0; j < 8; ++j) { xo[j] = f32_to_bf16_rne(xv[j]); io8[j] = (unsigned short)iv[j]; }
    *(uint4*)(xb16 + (size_t)b * IN_SZ + c) = *(uint4*)xo;
    *(uint4*)(idxh + (size_t)b * IN_SZ + c) = *(uint4*)io8;
}

// ---------------- prep 3: Wt[o][q*IN+i] = bf16(W[q*IN+i][o])  (transpose+convert) ----
__global__ void k_build_wt(const float* __restrict__ W, unsigned short* __restrict__ Wt) {
    __shared__ float tile[64][65];                 // +1 pad breaks bank conflicts
    int t = threadIdx.x;
    int k0 = blockIdx.x * 64;                      // 256 k-tiles
    int o0 = blockIdx.y * 64;                      // 16 o-tiles
#pragma unroll
    for (int it = 0; it < 4; ++it) {
        int F = it * 256 + t;                      // 1024 float4 loads
        int row = F >> 4;
        int c4  = (F & 15) * 4;
        float4 v = *(const float4*)(W + (size_t)(k0 + row) * OUT_SZ + o0 + c4);
        tile[row][c4 + 0] = v.x; tile[row][c4 + 1] = v.y;
        tile[row][c4 + 2] = v.z; tile[row][c4 + 3] = v.w;
    }
    __syncthreads();
#pragma unroll
    for (int it = 0; it < 2; ++it) {
        int G = it * 256 + t;                      // 512 uint4 stores
        int oo = G >> 3;
        int kc = (G & 7) * 8;
        unsigned short ov[8];
#pragma unroll
        for (int j = 0; j < 8; ++j) ov[j] = f32_to_bf16_rne(tile[kc + j][oo]);
        *(uint4*)(Wt + (size_t)(o0 + oo) * K_EXP + k0 + kc) = *(uint4*)ov;
    }
}

// ---------------- fused GEMM: out += maskq(x) @ Wt^T over the block's i-window ----
// z-block owns i in [zb*128, zb*128+128), ALL q. 32 steps = 2 i-halves x 16 q.
// Wt LDS-staged in a TRI-buffer with raw s_barrier + vmcnt(4): staging issued at
// step s lands at s+2, so the barrier never drains in-flight loads. x/idx live in
// registers. Wave tile: 32 b-rows x 128 o-cols (2 mt x 8 nt of 16x16x32 MFMA).
__global__ __launch_bounds__(256, 3) void k_gemm(const unsigned short* __restrict__ Wt,
                                                 const unsigned short* __restrict__ xb16,
                                                 const unsigned short* __restrict__ idxh,
                                                 float* __restrict__ out) {
    __shared__ unsigned short Blds[3 * 128 * 64];  // 48 KB tri-buffer
    const int tid  = threadIdx.x;
    const int wave = tid >> 6, lane = tid & 63;

    // 1-D grid, id = zb + 8*xb + 64*yb -> XCD (id%8) = zb: all blocks on one XCD
    // share the same Wt column window (4 MB = exactly one XCD L2).
    const int id = blockIdx.x;
    const int zb = id & 7;
    const int o0 = ((id >> 3) & 7) * 128;
    const int b0 = (id >> 6) * 128;
    const int ibase = zb * 128;                    // i-window

    // Wt staging: wave w rows [w*32+g*8+lrow], 128B rows = 8 chunks, slot = c^(row&7)
    const int lrow = lane >> 3, lcol = lane & 7;
    const int scol = lcol ^ lrow;
    const unsigned short* wS = Wt + (size_t)(o0 + wave * 32 + lrow) * K_EXP + ibase + scol * 8;
    const int wOff = wave * 4096;                  // wave's quarter within a buffer

    // B-frag offsets: row = nt*16 + (lane&15); chunk c = h*4 + quad at slot c^(lane&7)
    int nb[8];
#pragma unroll
    for (int nt = 0; nt < 8; ++nt) nb[nt] = (nt * 16 + (lane & 15)) * 128;
    int so[2];
#pragma unroll
    for (int h = 0; h < 2; ++h) so[h] = (((h << 2) | (lane >> 4)) ^ lcol) * 16;

    // A-side: row b0 + wave*32 + mt*16 + (lane&15); k-bytes per (h,quad) cover a full line
    const int arow = b0 + wave * 32 + (lane & 15);
    const unsigned short* xg = xb16 + (size_t)arow * IN_SZ + ibase + (lane >> 4) * 8;
    const unsigned short* ig = idxh + (size_t)arow * IN_SZ + ibase + (lane >> 4) * 8;

    floatx4 acc[16];
#pragma unroll
    for (int i = 0; i < 16; ++i) acc[i] = (floatx4){0.f, 0.f, 0.f, 0.f};

    // stage step t into buffer bf: Wt cols (t&15)*1024 + ((t>>4)&1)*64 in window
#define STAGE(t, bf)                                                          \
    {   int cw_ = ((t) & 15) * 1024 + ((((t) >> 4)) & 1) * 64;                \
        char* d_ = (char*)Blds + (bf) * 16384 + wOff;                         \
        _Pragma("unroll")                                                     \
        for (int g_ = 0; g_ < 4; ++g_)                                        \
            gll16(wS + cw_ + (size_t)g_ * 8 * K_EXP, d_ + g_ * 1024);         \
    }

    STAGE(0, 0);
    STAGE(1, 1);
    int pb = 0, sb = 2;                            // compute-buf, stage-buf (mod 3)
    uint4 xr[2][2], ir[2][2];

    for (int s = 0; s < 32; ++s) {
        // Need STAGE(s) landed. Steady state: newest 4 vmem = STAGE(s+1) -> vmcnt(4).
        if (s < 31) bar_vm4(); else bar_vm0();
        if ((s & 15) == 0) {                       // new i-half: reload A regs
            int io = (s >> 4) * 64;
#pragma unroll
            for (int mt = 0; mt < 2; ++mt)
#pragma unroll
                for (int h = 0; h < 2; ++h) {
                    xr[mt][h] = *(const uint4*)(xg + mt * 16 * IN_SZ + io + h * 32);
                    ir[mt][h] = *(const uint4*)(ig + mt * 16 * IN_SZ + io + h * 32);
                }
        }
        if (s < 30) STAGE(s + 2, sb);              // lands by step s+2 (2 phases away)
        const uint32_t qq = (uint32_t)(s & 15) * 0x00010001u;
        const char* bB = (const char*)Blds + pb * 16384;
#pragma unroll
        for (int h = 0; h < 2; ++h) {
            union { uint4 u; short8 s8; } aF[2];
#pragma unroll
            for (int mt = 0; mt < 2; ++mt) {
                aF[mt].u.x = mask2(xr[mt][h].x, ir[mt][h].x, qq);
                aF[mt].u.y = mask2(xr[mt][h].y, ir[mt][h].y, qq);
                aF[mt].u.z = mask2(xr[mt][h].z, ir[mt][h].z, qq);
                aF[mt].u.w = mask2(xr[mt][h].w, ir[mt][h].w, qq);
            }
            short8 bF[8];
#pragma unroll
            for (int nt = 0; nt < 8; ++nt) bF[nt] = *(const short8*)(bB + nb[nt] + so[h]);
#pragma unroll
            for (int mt = 0; mt < 2; ++mt)
#pragma unroll
                for (int nt = 0; nt < 8; ++nt)
                    acc[mt * 8 + nt] = __builtin_amdgcn_mfma_f32_16x16x32_bf16(
                        aF[mt].s8, bF[nt], acc[mt * 8 + nt], 0, 0, 0);
        }
        pb = (pb == 2) ? 0 : pb + 1;
        sb = (sb == 2) ? 0 : sb + 1;
    }

    // epilogue: C/D col=lane&15 (o), row=(lane>>4)*4+reg (b)
    int cn = lane & 15, rq = lane >> 4;
#pragma unroll
    for (int mt = 0; mt < 2; ++mt)
#pragma unroll
        for (int nt = 0; nt < 8; ++nt) {
            int bb = b0 + wave * 32 + mt * 16 + rq * 4;
            int oo = o0 + nt * 16 + cn;
#pragma unroll
            for (int e = 0; e < 4; ++e)
                atomicAdd(out + (size_t)(bb + e) * OUT_SZ + oo, acc[mt * 8 + nt][e]);
        }
#undef STAGE
}

// ---------------- fallback (ws too small): exact fp32 gather ----------------
__global__ void k_naive(const float* __restrict__ x, const int* __restrict__ idx,
                        const float* __restrict__ W, const float* __restrict__ bias,
                        float* __restrict__ out) {
    int b = blockIdx.x;
    int o = threadIdx.x * 4;
    float4 acc = *(const float4*)(bias + o);
    const float* xr = x + (size_t)b * IN_SZ;
    const int*   ir = idx + (size_t)b * IN_SZ;
    for (int i = 0; i < IN_SZ; ++i) {
        float xv = xr[i];
        int q = ir[i];
        float4 w4 = *(const float4*)(W + ((size_t)q * IN_SZ + i) * OUT_SZ + o);
        acc.x += xv * w4.x; acc.y += xv * w4.y;
        acc.z += xv * w4.z; acc.w += xv * w4.w;
    }
    *(float4*)(out + (size_t)b * OUT_SZ + o) = acc;
}

extern "C" void kernel_launch(void* const* d_in, const int* in_sizes, int n_in,
                              void* d_out, int out_size, void* d_ws, size_t ws_size,
                              hipStream_t stream) {
    const float* x    = (const float*)d_in[0];
    const int*   idx  = (const int*)d_in[1];
    const float* W    = (const float*)d_in[2];
    const float* bias = (const float*)d_in[3];
    float* out = (float*)d_out;

    const size_t wt_elems = (size_t)OUT_SZ * K_EXP;          // 16M u16 = 32 MB
    const size_t x_elems  = (size_t)B_SZ * IN_SZ;            // 2M u16 = 4 MB
    if (ws_size < (wt_elems + 2 * x_elems) * sizeof(unsigned short)) {
        k_naive<<<dim3(B_SZ), dim3(256), 0, stream>>>(x, idx, W, bias, out);
        return;
    }
    unsigned short* Wt   = (unsigned short*)d_ws;
    unsigned short* xb16 = Wt + wt_elems;
    unsigned short* idxh = xb16 + x_elems;

    k_init_out<<<dim3(2048), dim3(256), 0, stream>>>(out, bias);
    k_prep_xi<<<dim3(1024), dim3(256), 0, stream>>>(x, idx, xb16, idxh);
    k_build_wt<<<dim3(256, 16), dim3(256), 0, stream>>>(W, Wt);
    k_gemm<<<dim3(8 * 8 * (B_SZ / 128)), dim3(256), 0, stream>>>(Wt, xb16, idxh, out);
}